// Round 7
// baseline (327.465 us; speedup 1.0000x reference)
//
#include <hip/hip_runtime.h>
#include <math.h>

// SpectralConvLayer: spd[b,o,i,j] = sum_{c,n,d} u[c,n,i,d] * D[b,c,n,d]*|w[d,c,n,o]| * u[c,n,j,d]
// u = left singular vectors of C[c,n] (descending sigma); column signs cancel.
//
// eig: one-sided Jacobi (Hestenes) on C's columns, 4 waves per matrix, UNPIPELINED,
//   parity-double-buffered dot exchange -> ONE barrier per round.
//   Wave w holds rows [16w,16w+16) of all 64 columns; lane j owns column j's quarter.
//   XOR pair schedule m=1..63. Per round: bpermute partner slice+norm -> partial dot
//   -> write pex[par] -> BARRIER -> canonical sum -> rotate in-register.
//   WAR safety without a 2nd barrier: slot `par` is re-written only in round r+2,
//   and round r+1's barrier sits between round r's reads and that write.
//   (R4/R5's fused fetch-update pipeline diverged (absmax ~5.7 saturated) — do NOT
//   fuse next-round bpermute fetches into the update loop.)
//
// NSWEEP=8: proven floor (0.0078) at 1w/2w/4w; NSWEEP=6 FAILS (5.7). 7 untested.
//
// B=32, CENT=2, IN_CH=8 (16 matrices), OUT_CH=16, NDIAG=64.

#define NSWEEP 8
#define NROUND (NSWEEP * 63)   // 504

__device__ __forceinline__ float bper(int paddr, float v) {
    return __int_as_float(__builtin_amdgcn_ds_bpermute(paddr, __float_as_int(v)));
}

__device__ __forceinline__ float pdot16(const float (&a)[16], const float (&b)[16]) {
    float d0 = 0.f, d1 = 0.f, d2 = 0.f, d3 = 0.f;
    #pragma unroll
    for (int i = 0; i < 16; i += 4) {
        d0 = fmaf(a[i],     b[i],     d0);
        d1 = fmaf(a[i + 1], b[i + 1], d1);
        d2 = fmaf(a[i + 2], b[i + 2], d2);
        d3 = fmaf(a[i + 3], b[i + 3], d3);
    }
    return (d0 + d1) + (d2 + d3);
}

__global__ __launch_bounds__(256, 1) void eig_kernel(const float* __restrict__ C,
                                                     float* __restrict__ ut) {
    __shared__ float pex[2][4][64];   // [parity][wave][lane]
    __shared__ float sn[64];

    const int mat  = blockIdx.x;          // cn
    const int tid  = threadIdx.x;
    const int wv   = tid >> 6;            // wave 0..3
    const int lane = tid & 63;            // owns column `lane`
    const int row0 = wv << 4;             // this wave's row quarter
    const float* Cm = C + mat * 4096;

    float g[16];
    #pragma unroll
    for (int i = 0; i < 16; i++) g[i] = Cm[(row0 + i) * 64 + lane];

    // initial full squared norm via slot 0; round 0 writes slot 1 (disjoint),
    // and round 1's write of slot 0 is fenced by round 0's barrier.
    float nrm;
    {
        pex[0][wv][lane] = pdot16(g, g);
        __syncthreads();
        nrm = (pex[0][0][lane] + pex[0][1][lane]) + (pex[0][2][lane] + pex[0][3][lane]);
    }

    int m = 1;
    int par = 1;                          // round 0 -> slot 1
    for (int r = 0; r < NROUND; ++r) {
        const int partner = lane ^ m;
        const int paddr   = partner << 2;

        // fetch partner quarter-column + partner norm (in-wave, lockstep)
        float tmp[16];
        #pragma unroll
        for (int i = 0; i < 16; i++) tmp[i] = bper(paddr, g[i]);
        const float pn = bper(paddr, nrm);

        // partial dot + exchange (single barrier; parity slot)
        pex[par][wv][lane] = pdot16(g, tmp);

        // gam-independent rotation pieces, hoisted above the barrier
        const bool  is_p = lane < partner;
        const float diff = pn - nrm;                       // p: nqq-npp ; q: -(...)
        const float num  = is_p ? diff : -diff;

        __syncthreads();                                   // RAW fence for this slot
        const float gam = (pex[par][0][lane] + pex[par][1][lane]) +
                          (pex[par][2][lane] + pex[par][3][lane]);

        // rotation zeroing the implicit Gram off-diagonal (identical on all waves:
        // gam canonical order, nrm replicated, pn = bper of replicated nrm)
        const float zeta = num * 0.5f * __builtin_amdgcn_rcpf(gam);
        const float t0   = copysignf(1.f, zeta) *
                           __builtin_amdgcn_rcpf(fabsf(zeta) + sqrtf(fmaf(zeta, zeta, 1.f)));
        const float t    = (fabsf(gam) > 1e-30f) ? t0 : 0.f;   // select kills inf/nan path
        const float c    = __builtin_amdgcn_rsqf(fmaf(t, t, 1.f));
        const float s    = t * c;
        const float sa   = is_p ? -s : s;                  // g'_p = c g_p - s g_q ; g'_q = s g_p + c g_q
        const float ta   = is_p ? -t : t;                  // analytic ||g'||^2 update

        #pragma unroll
        for (int i = 0; i < 16; i++) g[i] = fmaf(c, g[i], sa * tmp[i]);
        nrm = fmaf(ta, gam, nrm);

        m = (m == 63) ? 1 : m + 1;
        par ^= 1;
    }

    // exact final norm (analytic update drifts over 504 rounds).
    // Extra leading barrier fences the last round's slot reads.
    {
        const float part = pdot16(g, g);
        __syncthreads();
        pex[0][wv][lane] = part;
        __syncthreads();
        nrm = (pex[0][0][lane] + pex[0][1][lane]) + (pex[0][2][lane] + pex[0][3][lane]);
    }

    // rank columns by descending sigma^2, index tiebreak (nrm replicated across waves)
    if (wv == 0) sn[lane] = nrm;
    __syncthreads();
    int rank = 0;
    #pragma unroll 8
    for (int e = 0; e < 64; e++) {
        const float ne = sn[e];
        rank += (ne > nrm) || (ne == nrm && e < lane);
    }

    // ut[mat][rank][row] = g[row]/sigma
    const float inv = __builtin_amdgcn_rsqf(fmaxf(nrm, 1e-30f));
    float* dst = ut + (mat * 64 + rank) * 64 + row0;
    #pragma unroll
    for (int i = 0; i < 16; i++) dst[i] = g[i] * inv;
}

// ---------------- Kernel 2: spd accumulation (LDS-return-BW bound, ~72 us) ----------------
__global__ __launch_bounds__(256) void spd_kernel(const float* __restrict__ D,
                                                  const float* __restrict__ w,
                                                  const float* __restrict__ ut,
                                                  float* __restrict__ out) {
    __shared__ __align__(16) float U[64][64];   // U[d][i]
    __shared__ float t[64];

    const int bid = blockIdx.x;
    const int b = bid >> 4, o = bid & 15;
    const int tid = threadIdx.x;
    const int ti = tid & 15, tj = tid >> 4;

    float acc[4][4] = {{0.f, 0.f, 0.f, 0.f}, {0.f, 0.f, 0.f, 0.f},
                       {0.f, 0.f, 0.f, 0.f}, {0.f, 0.f, 0.f, 0.f}};

    for (int cn = 0; cn < 16; cn++) {
        __syncthreads();   // protect U/t from previous iteration's readers
        const float4* src = (const float4*)(ut + cn * 4096);
        float4* dstU = (float4*)(&U[0][0]);
        #pragma unroll
        for (int idx = tid; idx < 1024; idx += 256) dstU[idx] = src[idx];
        if (tid < 64) {
            int d = tid;
            float dv = D[(b * 16 + cn) * 64 + d];
            float wv = fabsf(w[(d * 16 + cn) * 16 + o]);
            t[d] = dv * wv;
        }
        __syncthreads();

        #pragma unroll 4
        for (int d = 0; d < 64; d++) {
            float td = t[d];
            float4 uiv = *(const float4*)(&U[d][ti * 4]);
            float4 ujv = *(const float4*)(&U[d][tj * 4]);
            float si0 = td * uiv.x, si1 = td * uiv.y, si2 = td * uiv.z, si3 = td * uiv.w;
            acc[0][0] += si0 * ujv.x; acc[0][1] += si0 * ujv.y; acc[0][2] += si0 * ujv.z; acc[0][3] += si0 * ujv.w;
            acc[1][0] += si1 * ujv.x; acc[1][1] += si1 * ujv.y; acc[1][2] += si1 * ujv.z; acc[1][3] += si1 * ujv.w;
            acc[2][0] += si2 * ujv.x; acc[2][1] += si2 * ujv.y; acc[2][2] += si2 * ujv.z; acc[2][3] += si2 * ujv.w;
            acc[3][0] += si3 * ujv.x; acc[3][1] += si3 * ujv.y; acc[3][2] += si3 * ujv.z; acc[3][3] += si3 * ujv.w;
        }
    }

    float* obase = out + (size_t)bid * 4096;
    #pragma unroll
    for (int k = 0; k < 4; k++) {
        float4 v = make_float4(acc[k][0], acc[k][1], acc[k][2], acc[k][3]);
        *(float4*)(&obase[(ti * 4 + k) * 64 + tj * 4]) = v;
    }
}

extern "C" void kernel_launch(void* const* d_in, const int* in_sizes, int n_in,
                              void* d_out, int out_size, void* d_ws, size_t ws_size,
                              hipStream_t stream) {
    const float* D = (const float*)d_in[0];   // (32,2,8,64)
    const float* C = (const float*)d_in[1];   // (2,8,64,64)
    const float* w = (const float*)d_in[2];   // (64,2,8,16)
    float* out = (float*)d_out;               // (32,16,64,64)
    float* ut  = (float*)d_ws;                // 16*64*64 floats = 256 KB

    hipLaunchKernelGGL(eig_kernel, dim3(16), dim3(256), 0, stream, C, ut);
    hipLaunchKernelGGL(spd_kernel, dim3(512), dim3(256), 0, stream, D, w, ut, out);
}

// Round 8
// 303.283 us; speedup vs baseline: 1.0797x; 1.0797x over previous
//
#include <hip/hip_runtime.h>
#include <math.h>

// SpectralConvLayer: spd[b,o,i,j] = sum_{c,n,d} u[c,n,i,d] * D[b,c,n,d]*|w[d,c,n,o]| * u[c,n,j,d]
// u = left singular vectors of C[c,n] (descending sigma); column signs cancel.
//
// eig (R6-proven, 243us): one-sided Jacobi (Hestenes), 4 waves/matrix, UNPIPELINED,
//   single pex slot, TWO barriers/round. Round time is a fixed latency chain
//   (~1160cyc) invariant to wave count/pipelining/barriers (R3/R6/R7 all equal);
//   R7's 1-barrier parity variant was NOT faster — keep this one.
//   (R4/R5's fused fetch-update pipeline diverged (absmax ~5.7) — do NOT refuse.)
// NSWEEP=8: floor (0.0078) at 1w/2w/4w; NSWEEP=6 FAILS (5.7). Do not reduce.
//
// spd: per-CU DS-pipe bound. 8x8 register tiles (halves ds_read/MAC vs 4x4),
//   4 waves share one (b,o) and one LDS U-tile, splitting d 16-each (each U row
//   read by exactly one wave), then a 2-chunk LDS reduction combines the 4 accs.
//
// B=32, CENT=2, IN_CH=8 (16 matrices), OUT_CH=16, NDIAG=64.

#define NSWEEP 8
#define NROUND (NSWEEP * 63)   // 504

__device__ __forceinline__ float bper(int paddr, float v) {
    return __int_as_float(__builtin_amdgcn_ds_bpermute(paddr, __float_as_int(v)));
}

__device__ __forceinline__ float pdot16(const float (&a)[16], const float (&b)[16]) {
    float d0 = 0.f, d1 = 0.f, d2 = 0.f, d3 = 0.f;
    #pragma unroll
    for (int i = 0; i < 16; i += 4) {
        d0 = fmaf(a[i],     b[i],     d0);
        d1 = fmaf(a[i + 1], b[i + 1], d1);
        d2 = fmaf(a[i + 2], b[i + 2], d2);
        d3 = fmaf(a[i + 3], b[i + 3], d3);
    }
    return (d0 + d1) + (d2 + d3);
}

__global__ __launch_bounds__(256, 1) void eig_kernel(const float* __restrict__ C,
                                                     float* __restrict__ ut) {
    __shared__ float pex[4][64];
    __shared__ float sn[64];

    const int mat  = blockIdx.x;          // cn
    const int tid  = threadIdx.x;
    const int wv   = tid >> 6;            // wave 0..3
    const int lane = tid & 63;            // owns column `lane`
    const int row0 = wv << 4;             // this wave's row quarter
    const float* Cm = C + mat * 4096;

    float g[16];
    #pragma unroll
    for (int i = 0; i < 16; i++) g[i] = Cm[(row0 + i) * 64 + lane];

    // initial full squared norm: partials -> barrier -> canonical sum -> barrier
    float nrm;
    {
        pex[wv][lane] = pdot16(g, g);
        __syncthreads();
        nrm = (pex[0][lane] + pex[1][lane]) + (pex[2][lane] + pex[3][lane]);
        __syncthreads();
    }

    int m = 1;
    for (int r = 0; r < NROUND; ++r) {
        const int partner = lane ^ m;
        const int paddr   = partner << 2;

        // fetch partner quarter-column + partner norm (pre-rotation, lockstep in-wave)
        float tmp[16];
        #pragma unroll
        for (int i = 0; i < 16; i++) tmp[i] = bper(paddr, g[i]);
        const float pn = bper(paddr, nrm);

        // cross-wave exchange of the pair's dot product
        const float part = pdot16(g, tmp);
        pex[wv][lane] = part;
        __syncthreads();                                   // RAW: all partials visible
        const float gam = (pex[0][lane] + pex[1][lane]) + (pex[2][lane] + pex[3][lane]);
        __syncthreads();                                   // WAR: reads done before next write

        // rotation zeroing the implicit Gram off-diagonal (identical on all waves:
        // gam canonical, nrm replicated, pn = bper of replicated nrm)
        const bool  is_p = lane < partner;
        const float diff = pn - nrm;                       // p: nqq-npp ; q: -(...)
        const float num  = is_p ? diff : -diff;
        const float zeta = num * 0.5f * __builtin_amdgcn_rcpf(gam);
        const float t0   = copysignf(1.f, zeta) *
                           __builtin_amdgcn_rcpf(fabsf(zeta) + sqrtf(fmaf(zeta, zeta, 1.f)));
        const float t    = (fabsf(gam) > 1e-30f) ? t0 : 0.f;   // select kills inf/nan path
        const float c    = __builtin_amdgcn_rsqf(fmaf(t, t, 1.f));
        const float s    = t * c;
        const float sa   = is_p ? -s : s;                  // g'_p = c g_p - s g_q ; g'_q = s g_p + c g_q
        const float ta   = is_p ? -t : t;                  // analytic ||g'||^2 update

        #pragma unroll
        for (int i = 0; i < 16; i++) g[i] = fmaf(c, g[i], sa * tmp[i]);
        nrm = fmaf(ta, gam, nrm);

        m = (m == 63) ? 1 : m + 1;
    }

    // exact final norm (analytic update drifts over 504 rounds)
    {
        const float part = pdot16(g, g);
        pex[wv][lane] = part;          // safe: last round's reads closed by its 2nd barrier
        __syncthreads();
        nrm = (pex[0][lane] + pex[1][lane]) + (pex[2][lane] + pex[3][lane]);
    }

    // rank columns by descending sigma^2, index tiebreak (nrm replicated across waves)
    if (wv == 0) sn[lane] = nrm;
    __syncthreads();
    int rank = 0;
    #pragma unroll 8
    for (int e = 0; e < 64; e++) {
        const float ne = sn[e];
        rank += (ne > nrm) || (ne == nrm && e < lane);
    }

    // ut[mat][rank][row] = g[row]/sigma
    const float inv = __builtin_amdgcn_rsqf(fmaxf(nrm, 1e-30f));
    float* dst = ut + (mat * 64 + rank) * 64 + row0;
    #pragma unroll
    for (int i = 0; i < 16; i++) dst[i] = g[i] * inv;
}

// ---------------- Kernel 2: spd accumulation ----------------
// 512 blocks = (b,o); 4 waves/block share one LDS U-tile, each wave owns a d-quarter.
// Lane: ti=lane&7, tj=lane>>3 -> 8x8 output tile (i0=ti*8, j0=tj*8).
// Per d: 4x ds_read_b128 (16 floats) feed 64 MACs (half the DS/MAC of 4x4 tiling).
// Epilogue: 2-chunk LDS reduction of the 4 per-wave accumulators.
__global__ __launch_bounds__(256) void spd_kernel(const float* __restrict__ D,
                                                  const float* __restrict__ w,
                                                  const float* __restrict__ ut,
                                                  float* __restrict__ out) {
    __shared__ __align__(16) float U[64][64];   // U[d][i]
    __shared__ float ts[64];
    __shared__ float red[4][32][64];            // [wave][local r*8+c][lane], 32 KB/chunk

    const int bid  = blockIdx.x;
    const int b    = bid >> 4, o = bid & 15;
    const int tid  = threadIdx.x;
    const int wv   = tid >> 6;
    const int lane = tid & 63;
    const int ti   = lane & 7, tj = lane >> 3;
    const int d0   = wv << 4;                   // this wave's d-quarter

    float acc[8][8];
    #pragma unroll
    for (int r = 0; r < 8; r++)
        #pragma unroll
        for (int c = 0; c < 8; c++) acc[r][c] = 0.f;

    for (int cn = 0; cn < 16; cn++) {
        __syncthreads();   // WAR: previous iteration's readers done
        // stage ut[cn] (16 KB) into LDS: 1024 float4 by 256 threads
        const float4* src = (const float4*)(ut + cn * 4096);
        float4* dU = (float4*)(&U[0][0]);
        #pragma unroll
        for (int k = 0; k < 4; k++) dU[tid + k * 256] = src[tid + k * 256];
        if (tid < 64) {
            const int d = tid;
            const float dv = D[(b * 16 + cn) * 64 + d];
            const float wva = fabsf(w[(d * 16 + cn) * 16 + o]);
            ts[d] = dv * wva;
        }
        __syncthreads();   // RAW: U/ts visible

        #pragma unroll 4
        for (int dd = 0; dd < 16; dd++) {
            const int d = d0 + dd;
            const float td = ts[d];
            const float4* row = (const float4*)(&U[d][0]);
            const float4 a0 = row[ti * 2], a1 = row[ti * 2 + 1];
            const float4 b0 = row[tj * 2], b1 = row[tj * 2 + 1];
            const float si[8] = {td * a0.x, td * a0.y, td * a0.z, td * a0.w,
                                 td * a1.x, td * a1.y, td * a1.z, td * a1.w};
            const float bb[8] = {b0.x, b0.y, b0.z, b0.w, b1.x, b1.y, b1.z, b1.w};
            #pragma unroll
            for (int r = 0; r < 8; r++)
                #pragma unroll
                for (int c = 0; c < 8; c++) acc[r][c] = fmaf(si[r], bb[c], acc[r][c]);
        }
    }

    // reduce 4 per-wave accs -> out, in 2 chunks of 4 acc-rows (32 KB LDS each)
    float* ob = out + (size_t)bid * 4096;
    for (int chunk = 0; chunk < 2; chunk++) {
        __syncthreads();   // chunk0: main-loop done; chunk1: WAR on red
        #pragma unroll
        for (int rr = 0; rr < 4; rr++)
            #pragma unroll
            for (int c = 0; c < 8; c++)
                red[wv][rr * 8 + c][lane] = acc[chunk * 4 + rr][c];
        __syncthreads();   // RAW on red
        // 2048 outputs, 8 per thread: flat f = lane_*32 + rr*8 + c
        #pragma unroll
        for (int e = 0; e < 8; e++) {
            const int f   = tid * 8 + e;
            const int lf  = f >> 5;          // source lane
            const int loc = f & 31;          // rr*8+c
            const float v = (red[0][loc][lf] + red[1][loc][lf]) +
                            (red[2][loc][lf] + red[3][loc][lf]);
            const int c_  = f & 7;
            const int rr_ = (f >> 3) & 3;
            const int ti_ = (f >> 5) & 7;
            const int tj_ = f >> 8;
            const int i   = ti_ * 8 + chunk * 4 + rr_;
            const int j   = tj_ * 8 + c_;
            ob[i * 64 + j] = v;
        }
    }
}

extern "C" void kernel_launch(void* const* d_in, const int* in_sizes, int n_in,
                              void* d_out, int out_size, void* d_ws, size_t ws_size,
                              hipStream_t stream) {
    const float* D = (const float*)d_in[0];   // (32,2,8,64)
    const float* C = (const float*)d_in[1];   // (2,8,64,64)
    const float* w = (const float*)d_in[2];   // (64,2,8,16)
    float* out = (float*)d_out;               // (32,16,64,64)
    float* ut  = (float*)d_ws;                // 16*64*64 floats = 256 KB

    hipLaunchKernelGGL(eig_kernel, dim3(16), dim3(256), 0, stream, C, ut);
    hipLaunchKernelGGL(spd_kernel, dim3(512), dim3(256), 0, stream, D, w, ut, out);
}

// Round 10
// 273.786 us; speedup vs baseline: 1.1961x; 1.1077x over previous
//
#include <hip/hip_runtime.h>
#include <math.h>

// SpectralConvLayer: spd[b,o,i,j] = sum_{c,n,d} u[c,n,i,d] * D[b,c,n,d]*|w[d,c,n,o]| * u[c,n,j,d]
// u = left singular vectors of C[c,n] (descending sigma); column signs cancel.
//
// eig: one-sided Jacobi (Hestenes), 4 waves/matrix, UNPIPELINED, single pex slot,
//   TWO barriers/round (R6-proven). Round time is a fixed ~1160cyc latency chain
//   invariant to wave count/pipelining/barriers (R3/R6/R7 all equal).
//   ROTATION ALGEBRA MUST BE THE t=sgn*rcp(|z|+sqrt(1+z^2)) FORM: the
//   "rsqrt(1+u^2)" variant OVERFLOWS (u^2=inf when gam~1e-20 -> zeta~1e19) and
//   NaN'd the whole output in R9. Do not square |zeta|-scale quantities.
//   (R4/R5's fused fetch-update pipeline diverged (absmax ~5.7) — do NOT re-fuse.)
// NSWEEP: 8 = proven floor (0.0078) at 1w/2w/4w. 7 = THIS ROUND'S (clean) EXPERIMENT
//   — R9's NSWEEP=7 run was confounded by the overflow bug. If absmax > 0.05,
//   revert to 8 and eig is final at 243us.
//
// spd (R8-proven, ~60us): 8x8 register tiles, 4 waves share one (b,o)+LDS U-tile,
//   d split 16/wave, 2-chunk LDS reduction epilogue.
//
// B=32, CENT=2, IN_CH=8 (16 matrices), OUT_CH=16, NDIAG=64.

#define NSWEEP 7
#define NROUND (NSWEEP * 63)   // 441

__device__ __forceinline__ float bper(int paddr, float v) {
    return __int_as_float(__builtin_amdgcn_ds_bpermute(paddr, __float_as_int(v)));
}

__device__ __forceinline__ float pdot16(const float (&a)[16], const float (&b)[16]) {
    float d0 = 0.f, d1 = 0.f, d2 = 0.f, d3 = 0.f;
    #pragma unroll
    for (int i = 0; i < 16; i += 4) {
        d0 = fmaf(a[i],     b[i],     d0);
        d1 = fmaf(a[i + 1], b[i + 1], d1);
        d2 = fmaf(a[i + 2], b[i + 2], d2);
        d3 = fmaf(a[i + 3], b[i + 3], d3);
    }
    return (d0 + d1) + (d2 + d3);
}

__global__ __launch_bounds__(256, 1) void eig_kernel(const float* __restrict__ C,
                                                     float* __restrict__ ut) {
    __shared__ float pex[4][64];
    __shared__ float sn[64];

    const int mat  = blockIdx.x;          // cn
    const int tid  = threadIdx.x;
    const int wv   = tid >> 6;            // wave 0..3
    const int lane = tid & 63;            // owns column `lane`
    const int row0 = wv << 4;             // this wave's row quarter
    const float* Cm = C + mat * 4096;

    float g[16];
    #pragma unroll
    for (int i = 0; i < 16; i++) g[i] = Cm[(row0 + i) * 64 + lane];

    // initial full squared norm: partials -> barrier -> canonical sum -> barrier
    float nrm;
    {
        pex[wv][lane] = pdot16(g, g);
        __syncthreads();
        nrm = (pex[0][lane] + pex[1][lane]) + (pex[2][lane] + pex[3][lane]);
        __syncthreads();
    }

    int m = 1;
    for (int r = 0; r < NROUND; ++r) {
        const int partner = lane ^ m;
        const int paddr   = partner << 2;

        // fetch partner quarter-column + partner norm (pre-rotation, lockstep in-wave)
        float tmp[16];
        #pragma unroll
        for (int i = 0; i < 16; i++) tmp[i] = bper(paddr, g[i]);
        const float pn = bper(paddr, nrm);

        // cross-wave exchange of the pair's dot product
        const float part = pdot16(g, tmp);
        pex[wv][lane] = part;
        __syncthreads();                                   // RAW: all partials visible
        const float gam = (pex[0][lane] + pex[1][lane]) + (pex[2][lane] + pex[3][lane]);
        __syncthreads();                                   // WAR: reads done before next write

        // rotation zeroing the implicit Gram off-diagonal (identical on all waves:
        // gam canonical, nrm replicated, pn = bper of replicated nrm).
        // Overflow-safe proven chain — see header warning.
        const bool  is_p = lane < partner;
        const float diff = pn - nrm;                       // p: nqq-npp ; q: -(...)
        const float num  = is_p ? diff : -diff;
        const float zeta = num * 0.5f * __builtin_amdgcn_rcpf(gam);
        const float t0   = copysignf(1.f, zeta) *
                           __builtin_amdgcn_rcpf(fabsf(zeta) + sqrtf(fmaf(zeta, zeta, 1.f)));
        const float t    = (fabsf(gam) > 1e-30f) ? t0 : 0.f;   // select kills inf/nan path
        const float c    = __builtin_amdgcn_rsqf(fmaf(t, t, 1.f));
        const float s    = t * c;
        const float sa   = is_p ? -s : s;                  // g'_p = c g_p - s g_q ; g'_q = s g_p + c g_q
        const float ta   = is_p ? -t : t;                  // analytic ||g'||^2 update

        #pragma unroll
        for (int i = 0; i < 16; i++) g[i] = fmaf(c, g[i], sa * tmp[i]);
        nrm = fmaf(ta, gam, nrm);

        m = (m == 63) ? 1 : m + 1;
    }

    // exact final norm (analytic update drifts over 441 rounds)
    {
        const float part = pdot16(g, g);
        pex[wv][lane] = part;          // safe: last round's reads closed by its 2nd barrier
        __syncthreads();
        nrm = (pex[0][lane] + pex[1][lane]) + (pex[2][lane] + pex[3][lane]);
    }

    // rank columns by descending sigma^2, index tiebreak (nrm replicated across waves)
    if (wv == 0) sn[lane] = nrm;
    __syncthreads();
    int rank = 0;
    #pragma unroll 8
    for (int e = 0; e < 64; e++) {
        const float ne = sn[e];
        rank += (ne > nrm) || (ne == nrm && e < lane);
    }

    // ut[mat][rank][row] = g[row]/sigma
    const float inv = __builtin_amdgcn_rsqf(fmaxf(nrm, 1e-30f));
    float* dst = ut + (mat * 64 + rank) * 64 + row0;
    #pragma unroll
    for (int i = 0; i < 16; i++) dst[i] = g[i] * inv;
}

// ---------------- Kernel 2: spd accumulation ----------------
// 512 blocks = (b,o); 4 waves/block share one LDS U-tile, each wave owns a d-quarter.
// Lane: ti=lane&7, tj=lane>>3 -> 8x8 output tile (i0=ti*8, j0=tj*8).
// Per d: 4x ds_read_b128 (16 floats) feed 64 MACs (half the DS/MAC of 4x4 tiling).
// Epilogue: 2-chunk LDS reduction of the 4 per-wave accumulators.
__global__ __launch_bounds__(256) void spd_kernel(const float* __restrict__ D,
                                                  const float* __restrict__ w,
                                                  const float* __restrict__ ut,
                                                  float* __restrict__ out) {
    __shared__ __align__(16) float U[64][64];   // U[d][i]
    __shared__ float ts[64];
    __shared__ float red[4][32][64];            // [wave][local r*8+c][lane], 32 KB/chunk

    const int bid  = blockIdx.x;
    const int b    = bid >> 4, o = bid & 15;
    const int tid  = threadIdx.x;
    const int wv   = tid >> 6;
    const int lane = tid & 63;
    const int ti   = lane & 7, tj = lane >> 3;
    const int d0   = wv << 4;                   // this wave's d-quarter

    float acc[8][8];
    #pragma unroll
    for (int r = 0; r < 8; r++)
        #pragma unroll
        for (int c = 0; c < 8; c++) acc[r][c] = 0.f;

    for (int cn = 0; cn < 16; cn++) {
        __syncthreads();   // WAR: previous iteration's readers done
        // stage ut[cn] (16 KB) into LDS: 1024 float4 by 256 threads
        const float4* src = (const float4*)(ut + cn * 4096);
        float4* dU = (float4*)(&U[0][0]);
        #pragma unroll
        for (int k = 0; k < 4; k++) dU[tid + k * 256] = src[tid + k * 256];
        if (tid < 64) {
            const int d = tid;
            const float dv = D[(b * 16 + cn) * 64 + d];
            const float wva = fabsf(w[(d * 16 + cn) * 16 + o]);
            ts[d] = dv * wva;
        }
        __syncthreads();   // RAW: U/ts visible

        #pragma unroll 4
        for (int dd = 0; dd < 16; dd++) {
            const int d = d0 + dd;
            const float td = ts[d];
            const float4* row = (const float4*)(&U[d][0]);
            const float4 a0 = row[ti * 2], a1 = row[ti * 2 + 1];
            const float4 b0 = row[tj * 2], b1 = row[tj * 2 + 1];
            const float si[8] = {td * a0.x, td * a0.y, td * a0.z, td * a0.w,
                                 td * a1.x, td * a1.y, td * a1.z, td * a1.w};
            const float bb[8] = {b0.x, b0.y, b0.z, b0.w, b1.x, b1.y, b1.z, b1.w};
            #pragma unroll
            for (int r = 0; r < 8; r++)
                #pragma unroll
                for (int c = 0; c < 8; c++) acc[r][c] = fmaf(si[r], bb[c], acc[r][c]);
        }
    }

    // reduce 4 per-wave accs -> out, in 2 chunks of 4 acc-rows (32 KB LDS each)
    float* ob = out + (size_t)bid * 4096;
    for (int chunk = 0; chunk < 2; chunk++) {
        __syncthreads();   // chunk0: main-loop done; chunk1: WAR on red
        #pragma unroll
        for (int rr = 0; rr < 4; rr++)
            #pragma unroll
            for (int c = 0; c < 8; c++)
                red[wv][rr * 8 + c][lane] = acc[chunk * 4 + rr][c];
        __syncthreads();   // RAW on red
        // 2048 outputs, 8 per thread: flat f = lane_*32 + rr*8 + c
        #pragma unroll
        for (int e = 0; e < 8; e++) {
            const int f   = tid * 8 + e;
            const int lf  = f >> 5;          // source lane
            const int loc = f & 31;          // rr*8+c
            const float v = (red[0][loc][lf] + red[1][loc][lf]) +
                            (red[2][loc][lf] + red[3][loc][lf]);
            const int c_  = f & 7;
            const int rr_ = (f >> 3) & 3;
            const int ti_ = (f >> 5) & 7;
            const int tj_ = f >> 8;
            const int i   = ti_ * 8 + chunk * 4 + rr_;
            const int j   = tj_ * 8 + c_;
            ob[i * 64 + j] = v;
        }
    }
}

extern "C" void kernel_launch(void* const* d_in, const int* in_sizes, int n_in,
                              void* d_out, int out_size, void* d_ws, size_t ws_size,
                              hipStream_t stream) {
    const float* D = (const float*)d_in[0];   // (32,2,8,64)
    const float* C = (const float*)d_in[1];   // (2,8,64,64)
    const float* w = (const float*)d_in[2];   // (64,2,8,16)
    float* out = (float*)d_out;               // (32,16,64,64)
    float* ut  = (float*)d_ws;                // 16*64*64 floats = 256 KB

    hipLaunchKernelGGL(eig_kernel, dim3(16), dim3(256), 0, stream, C, ut);
    hipLaunchKernelGGL(spd_kernel, dim3(512), dim3(256), 0, stream, D, w, ut, out);
}

// Round 12
// 273.487 us; speedup vs baseline: 1.1974x; 1.0011x over previous
//
#include <hip/hip_runtime.h>
#include <math.h>

// SpectralConvLayer: spd[b,o,i,j] = sum_{c,n,d} u[c,n,i,d] * D[b,c,n,d]*|w[d,c,n,o]| * u[c,n,j,d]
// u = left singular vectors of C[c,n] (descending sigma); column signs cancel.
//
// eig: one-sided Jacobi (Hestenes), 4 waves/matrix, UNPIPELINED, single pex slot,
//   TWO barriers/round (R6-proven). Round time is a fixed ~1160cyc latency chain
//   invariant to wave count/pipelining/barriers (R3/R6/R7 all equal) — the only
//   validated lever is ROUND COUNT (R10: 504->441 scaled time exactly).
//   ROTATION ALGEBRA MUST BE THE t=sgn*rcp(|z|+sqrt(1+z^2)) FORM: the
//   "rsqrt(1+u^2)" variant OVERFLOWS (zeta~1e19 when gam~1e-20) and NaN'd R9.
//   (R4/R5's fused fetch-update pipeline diverged (absmax ~5.7) — do NOT re-fuse.)
// NSWEEP boundary FULLY MAPPED (clean experiments): 6 -> 0.21 FAIL (R11);
//   7 -> 0.0078 floor PASS (R10); 8 -> 0.0078 floor (R6/R8). NSWEEP=7 IS MINIMAL.
//
// spd (R8-proven, ~60us): 8x8 register tiles, 4 waves share one (b,o)+LDS U-tile,
//   d split 16/wave, 2-chunk LDS reduction epilogue.
//
// B=32, CENT=2, IN_CH=8 (16 matrices), OUT_CH=16, NDIAG=64.

#define NSWEEP 7
#define NROUND (NSWEEP * 63)   // 441

__device__ __forceinline__ float bper(int paddr, float v) {
    return __int_as_float(__builtin_amdgcn_ds_bpermute(paddr, __float_as_int(v)));
}

__device__ __forceinline__ float pdot16(const float (&a)[16], const float (&b)[16]) {
    float d0 = 0.f, d1 = 0.f, d2 = 0.f, d3 = 0.f;
    #pragma unroll
    for (int i = 0; i < 16; i += 4) {
        d0 = fmaf(a[i],     b[i],     d0);
        d1 = fmaf(a[i + 1], b[i + 1], d1);
        d2 = fmaf(a[i + 2], b[i + 2], d2);
        d3 = fmaf(a[i + 3], b[i + 3], d3);
    }
    return (d0 + d1) + (d2 + d3);
}

__global__ __launch_bounds__(256, 1) void eig_kernel(const float* __restrict__ C,
                                                     float* __restrict__ ut) {
    __shared__ float pex[4][64];
    __shared__ float sn[64];

    const int mat  = blockIdx.x;          // cn
    const int tid  = threadIdx.x;
    const int wv   = tid >> 6;            // wave 0..3
    const int lane = tid & 63;            // owns column `lane`
    const int row0 = wv << 4;             // this wave's row quarter
    const float* Cm = C + mat * 4096;

    float g[16];
    #pragma unroll
    for (int i = 0; i < 16; i++) g[i] = Cm[(row0 + i) * 64 + lane];

    // initial full squared norm: partials -> barrier -> canonical sum -> barrier
    float nrm;
    {
        pex[wv][lane] = pdot16(g, g);
        __syncthreads();
        nrm = (pex[0][lane] + pex[1][lane]) + (pex[2][lane] + pex[3][lane]);
        __syncthreads();
    }

    int m = 1;
    for (int r = 0; r < NROUND; ++r) {
        const int partner = lane ^ m;
        const int paddr   = partner << 2;

        // fetch partner quarter-column + partner norm (pre-rotation, lockstep in-wave)
        float tmp[16];
        #pragma unroll
        for (int i = 0; i < 16; i++) tmp[i] = bper(paddr, g[i]);
        const float pn = bper(paddr, nrm);

        // cross-wave exchange of the pair's dot product
        const float part = pdot16(g, tmp);
        pex[wv][lane] = part;
        __syncthreads();                                   // RAW: all partials visible
        const float gam = (pex[0][lane] + pex[1][lane]) + (pex[2][lane] + pex[3][lane]);
        __syncthreads();                                   // WAR: reads done before next write

        // rotation zeroing the implicit Gram off-diagonal (identical on all waves:
        // gam canonical, nrm replicated, pn = bper of replicated nrm).
        // Overflow-safe proven chain — see header warning.
        const bool  is_p = lane < partner;
        const float diff = pn - nrm;                       // p: nqq-npp ; q: -(...)
        const float num  = is_p ? diff : -diff;
        const float zeta = num * 0.5f * __builtin_amdgcn_rcpf(gam);
        const float t0   = copysignf(1.f, zeta) *
                           __builtin_amdgcn_rcpf(fabsf(zeta) + sqrtf(fmaf(zeta, zeta, 1.f)));
        const float t    = (fabsf(gam) > 1e-30f) ? t0 : 0.f;   // select kills inf/nan path
        const float c    = __builtin_amdgcn_rsqf(fmaf(t, t, 1.f));
        const float s    = t * c;
        const float sa   = is_p ? -s : s;                  // g'_p = c g_p - s g_q ; g'_q = s g_p + c g_q
        const float ta   = is_p ? -t : t;                  // analytic ||g'||^2 update

        #pragma unroll
        for (int i = 0; i < 16; i++) g[i] = fmaf(c, g[i], sa * tmp[i]);
        nrm = fmaf(ta, gam, nrm);

        m = (m == 63) ? 1 : m + 1;
    }

    // exact final norm (analytic update drifts over the rounds)
    {
        const float part = pdot16(g, g);
        pex[wv][lane] = part;          // safe: last round's reads closed by its 2nd barrier
        __syncthreads();
        nrm = (pex[0][lane] + pex[1][lane]) + (pex[2][lane] + pex[3][lane]);
    }

    // rank columns by descending sigma^2, index tiebreak (nrm replicated across waves)
    if (wv == 0) sn[lane] = nrm;
    __syncthreads();
    int rank = 0;
    #pragma unroll 8
    for (int e = 0; e < 64; e++) {
        const float ne = sn[e];
        rank += (ne > nrm) || (ne == nrm && e < lane);
    }

    // ut[mat][rank][row] = g[row]/sigma
    const float inv = __builtin_amdgcn_rsqf(fmaxf(nrm, 1e-30f));
    float* dst = ut + (mat * 64 + rank) * 64 + row0;
    #pragma unroll
    for (int i = 0; i < 16; i++) dst[i] = g[i] * inv;
}

// ---------------- Kernel 2: spd accumulation ----------------
// 512 blocks = (b,o); 4 waves/block share one LDS U-tile, each wave owns a d-quarter.
// Lane: ti=lane&7, tj=lane>>3 -> 8x8 output tile (i0=ti*8, j0=tj*8).
// Per d: 4x ds_read_b128 (16 floats) feed 64 MACs (half the DS/MAC of 4x4 tiling).
// Epilogue: 2-chunk LDS reduction of the 4 per-wave accumulators.
__global__ __launch_bounds__(256) void spd_kernel(const float* __restrict__ D,
                                                  const float* __restrict__ w,
                                                  const float* __restrict__ ut,
                                                  float* __restrict__ out) {
    __shared__ __align__(16) float U[64][64];   // U[d][i]
    __shared__ float ts[64];
    __shared__ float red[4][32][64];            // [wave][local r*8+c][lane], 32 KB/chunk

    const int bid  = blockIdx.x;
    const int b    = bid >> 4, o = bid & 15;
    const int tid  = threadIdx.x;
    const int wv   = tid >> 6;
    const int lane = tid & 63;
    const int ti   = lane & 7, tj = lane >> 3;
    const int d0   = wv << 4;                   // this wave's d-quarter

    float acc[8][8];
    #pragma unroll
    for (int r = 0; r < 8; r++)
        #pragma unroll
        for (int c = 0; c < 8; c++) acc[r][c] = 0.f;

    for (int cn = 0; cn < 16; cn++) {
        __syncthreads();   // WAR: previous iteration's readers done
        // stage ut[cn] (16 KB) into LDS: 1024 float4 by 256 threads
        const float4* src = (const float4*)(ut + cn * 4096);
        float4* dU = (float4*)(&U[0][0]);
        #pragma unroll
        for (int k = 0; k < 4; k++) dU[tid + k * 256] = src[tid + k * 256];
        if (tid < 64) {
            const int d = tid;
            const float dv = D[(b * 16 + cn) * 64 + d];
            const float wva = fabsf(w[(d * 16 + cn) * 16 + o]);
            ts[d] = dv * wva;
        }
        __syncthreads();   // RAW: U/ts visible

        #pragma unroll 4
        for (int dd = 0; dd < 16; dd++) {
            const int d = d0 + dd;
            const float td = ts[d];
            const float4* row = (const float4*)(&U[d][0]);
            const float4 a0 = row[ti * 2], a1 = row[ti * 2 + 1];
            const float4 b0 = row[tj * 2], b1 = row[tj * 2 + 1];
            const float si[8] = {td * a0.x, td * a0.y, td * a0.z, td * a0.w,
                                 td * a1.x, td * a1.y, td * a1.z, td * a1.w};
            const float bb[8] = {b0.x, b0.y, b0.z, b0.w, b1.x, b1.y, b1.z, b1.w};
            #pragma unroll
            for (int r = 0; r < 8; r++)
                #pragma unroll
                for (int c = 0; c < 8; c++) acc[r][c] = fmaf(si[r], bb[c], acc[r][c]);
        }
    }

    // reduce 4 per-wave accs -> out, in 2 chunks of 4 acc-rows (32 KB LDS each)
    float* ob = out + (size_t)bid * 4096;
    for (int chunk = 0; chunk < 2; chunk++) {
        __syncthreads();   // chunk0: main-loop done; chunk1: WAR on red
        #pragma unroll
        for (int rr = 0; rr < 4; rr++)
            #pragma unroll
            for (int c = 0; c < 8; c++)
                red[wv][rr * 8 + c][lane] = acc[chunk * 4 + rr][c];
        __syncthreads();   // RAW on red
        // 2048 outputs, 8 per thread: flat f = lane_*32 + rr*8 + c
        #pragma unroll
        for (int e = 0; e < 8; e++) {
            const int f   = tid * 8 + e;
            const int lf  = f >> 5;          // source lane
            const int loc = f & 31;          // rr*8+c
            const float v = (red[0][loc][lf] + red[1][loc][lf]) +
                            (red[2][loc][lf] + red[3][loc][lf]);
            const int c_  = f & 7;
            const int rr_ = (f >> 3) & 3;
            const int ti_ = (f >> 5) & 7;
            const int tj_ = f >> 8;
            const int i   = ti_ * 8 + chunk * 4 + rr_;
            const int j   = tj_ * 8 + c_;
            ob[i * 64 + j] = v;
        }
    }
}

extern "C" void kernel_launch(void* const* d_in, const int* in_sizes, int n_in,
                              void* d_out, int out_size, void* d_ws, size_t ws_size,
                              hipStream_t stream) {
    const float* D = (const float*)d_in[0];   // (32,2,8,64)
    const float* C = (const float*)d_in[1];   // (2,8,64,64)
    const float* w = (const float*)d_in[2];   // (64,2,8,16)
    float* out = (float*)d_out;               // (32,16,64,64)
    float* ut  = (float*)d_ws;                // 16*64*64 floats = 256 KB

    hipLaunchKernelGGL(eig_kernel, dim3(16), dim3(256), 0, stream, C, ut);
    hipLaunchKernelGGL(spd_kernel, dim3(512), dim3(256), 0, stream, D, w, ut, out);
}